// Round 19
// baseline (230.954 us; speedup 1.0000x reference)
//
#include <hip/hip_runtime.h>
#include <hip/hip_bf16.h>
#include <math.h>

typedef unsigned short u16;
typedef __attribute__((ext_vector_type(8))) __bf16 bf16x8;
typedef __attribute__((ext_vector_type(4))) float f32x4;

#define DIM   1024
#define LSEQ  2048
#define BTOK  4096
#define HD    64
#define FFN   4096
// 1/sqrt(64) * log2(e), folded into Q at projection time so softmax is pure exp2
#define QSCL  0.18033688011112042f

#if __has_builtin(__builtin_amdgcn_exp2f)
#define EXP2(x) __builtin_amdgcn_exp2f(x)
#else
#define EXP2(x) exp2f(x)
#endif

__device__ __forceinline__ u16 f2bf(float f) {
  unsigned u = __builtin_bit_cast(unsigned, f);
  u += 0x7FFFu + ((u >> 16) & 1u);
  return (u16)(u >> 16);
}
__device__ __forceinline__ unsigned pk2(float a, float b) {
  return (unsigned)f2bf(a) | ((unsigned)f2bf(b) << 16);
}
__device__ __forceinline__ unsigned cvtpk(float lo, float hi) {
  unsigned r;
  asm("v_cvt_pk_bf16_f32 %0, %1, %2" : "=v"(r) : "v"(lo), "v"(hi));
  return r;
}
__device__ __forceinline__ f32x4 mfma16(bf16x8 a, bf16x8 b, f32x4 c) {
  return __builtin_amdgcn_mfma_f32_16x16x32_bf16(a, b, c, 0, 0, 0);
}
__device__ __forceinline__ void gload16(const void* g, void* l) {
  __builtin_amdgcn_global_load_lds((const __attribute__((address_space(1))) char*)g,
                                   (__attribute__((address_space(3))) char*)l, 16, 0, 0);
}
// gelu (tanh form)
__device__ __forceinline__ float gelu_t(float v) {
  float v3 = v * v * v;
  float tt = fmaf(-0.10296766f, v3, -2.30258509f * v);
  return v * __builtin_amdgcn_rcpf(1.0f + EXP2(tt));
}

// ---------------- LayerNorm (fp32 in -> bf16 out) ----------------
__global__ __launch_bounds__(256) void ln_kernel(const float* __restrict__ x,
                                                 const float* __restrict__ g,
                                                 const float* __restrict__ bta,
                                                 u16* __restrict__ out) {
  int row = blockIdx.x, t = threadIdx.x;
  const float* xr = x + (size_t)row * DIM;
  float4 xv = *(const float4*)(xr + t * 4);
  float s  = xv.x + xv.y + xv.z + xv.w;
  float ss = xv.x * xv.x + xv.y * xv.y + xv.z * xv.z + xv.w * xv.w;
#pragma unroll
  for (int m = 32; m >= 1; m >>= 1) {
    s  += __shfl_xor(s, m);
    ss += __shfl_xor(ss, m);
  }
  __shared__ float red[8];
  if ((t & 63) == 0) { red[(t >> 6) * 2] = s; red[(t >> 6) * 2 + 1] = ss; }
  __syncthreads();
  s  = red[0] + red[2] + red[4] + red[6];
  ss = red[1] + red[3] + red[5] + red[7];
  float mu  = s * (1.0f / DIM);
  float var = ss * (1.0f / DIM) - mu * mu;
  float rs  = rsqrtf(var + 1e-5f);
  float4 gv = *(const float4*)(g + t * 4);
  float4 bv = *(const float4*)(bta + t * 4);
  uint2 o;
  o.x = pk2((xv.x - mu) * rs * gv.x + bv.x, (xv.y - mu) * rs * gv.y + bv.y);
  o.y = pk2((xv.z - mu) * rs * gv.z + bv.z, (xv.w - mu) * rs * gv.w + bv.w);
  *(uint2*)(out + (size_t)row * DIM + t * 4) = o;
}

// ---------------- weight fp32 -> bf16 ----------------
__global__ __launch_bounds__(256) void wcvt4(const float* __restrict__ Wq, const float* __restrict__ Wk,
                                             const float* __restrict__ Wv, const float* __restrict__ Wo,
                                             u16* __restrict__ dst) {
  int b = blockIdx.x;
  int r = b >> 9;
  const float* s = (r == 0) ? Wq : (r == 1) ? Wk : (r == 2) ? Wv : Wo;
  size_t i = (((size_t)(b & 511)) * 256 + threadIdx.x) * 8;
  float4 f0 = *(const float4*)(s + i), f1 = *(const float4*)(s + i + 4);
  uint4 o = { pk2(f0.x, f0.y), pk2(f0.z, f0.w), pk2(f1.x, f1.y), pk2(f1.z, f1.w) };
  *(uint4*)(dst + ((size_t)r << 20) + i) = o;
}
__global__ __launch_bounds__(256) void wcvt2(const float* __restrict__ W1, const float* __restrict__ W2,
                                             u16* __restrict__ d1, u16* __restrict__ d2) {
  int b = blockIdx.x;
  const float* s = (b < 2048) ? W1 : W2;
  u16* d = (b < 2048) ? d1 : d2;
  size_t i = (((size_t)(b & 2047)) * 256 + threadIdx.x) * 8;
  float4 f0 = *(const float4*)(s + i), f1 = *(const float4*)(s + i + 4);
  uint4 o = { pk2(f0.x, f0.y), pk2(f0.z, f0.w), pk2(f1.x, f1.y), pk2(f1.z, f1.w) };
  *(uint4*)(d + i) = o;
}

// ---------------- V transpose: v[b,l,h,c] -> vt[b,h,c,l] ----------------
__global__ __launch_bounds__(256) void transpose_v(const u16* __restrict__ v,
                                                   u16* __restrict__ vt) {
  __shared__ u16 tls[64][80];
  int jb = blockIdx.x, bh = blockIdx.y, b = bh >> 4, h = bh & 15;
  int t = threadIdx.x;
  int r = t >> 2, seg = t & 3;
  const u16* src = v + (size_t)(b * LSEQ + jb * 64 + r) * DIM + h * HD + seg * 16;
  *(uint4*)&tls[r][seg * 16]     = *(const uint4*)src;
  *(uint4*)&tls[r][seg * 16 + 8] = *(const uint4*)(src + 8);
  __syncthreads();
  int c = t >> 2, jseg = t & 3;
  u16 tmp[16] __attribute__((aligned(16)));
#pragma unroll
  for (int i = 0; i < 16; i++) tmp[i] = tls[jseg * 16 + i][c];
  u16* dst = vt + ((size_t)bh * HD + c) * LSEQ + jb * 64 + jseg * 16;
  *(uint4*)dst       = *(const uint4*)tmp;
  *(uint4*)(dst + 8) = *(const uint4*)(tmp + 8);
}

// ---------------- GEMM (round-5 proven, BK=32): C = A(bf16) @ W(bf16,[N,K])^T + bias ----------------
// EPI 0: outB = bf16((acc+bias)*oscale); 1: outF = acc+bias+resid (fp32); 2: outB = bf16(gelu(acc+bias))
struct GArg { const u16* Wb; const float* bias; u16* outB; float oscale; };

template <int EPI, int BM>
__global__ __launch_bounds__(256) void gemm3(const u16* __restrict__ A,
                                             GArg g0, GArg g1, GArg g2,
                                             const float* __restrict__ resid,
                                             float* __restrict__ outF,
                                             int N, int K, int nbPerW) {
  constexpr int WM = BM / 32;
  constexpr int ABUF = BM * 64;  // bytes per A double-buffer half
  __shared__ u16 lsa[2][BM * 32];
  __shared__ u16 lsb[2][128 * 32];
  const int t = threadIdx.x;
  const int w = t >> 6, l = t & 63, l15 = l & 15, lg = l >> 4;
  const int wr = w >> 1, wc = w & 1;
  // bijective XCD-chunk remap (all launch grids have nwg % 8 == 0)
  const int nwg = gridDim.x * gridDim.y;
  int flat = blockIdx.y * gridDim.x + blockIdx.x;
  flat = (flat & 7) * (nwg >> 3) + (flat >> 3);
  const int bx = flat % gridDim.x, by = flat / gridDim.x;
  const int sel = bx / nbPerW, nb = bx % nbPerW;
  GArg G = (sel == 0) ? g0 : ((sel == 1) ? g1 : g2);
  const int n0 = nb * 128, m0 = by * BM;

  f32x4 acc[WM][4];
#pragma unroll
  for (int m = 0; m < WM; m++)
#pragma unroll
    for (int n = 0; n < 4; n++) acc[m][n] = (f32x4){0.f, 0.f, 0.f, 0.f};

  // staging: linear LDS dest, pre-swizzled global source (chunk ^= (row>>1)&3)
  const int grow = t >> 2;
  const int gcol = 8 * ((t & 3) ^ ((t >> 3) & 3));
  const u16* Asrc = A + (size_t)(m0 + grow) * K + gcol;
  const u16* Bsrc = G.Wb + (size_t)(n0 + grow) * K + gcol;
  const int rs = (l15 >> 1) & 3;  // read-side swizzle key

  const char* aadr = (const char*)lsa + (wr * (BM / 2) + l15) * 64 + (lg ^ rs) * 16;
  const char* badr = (const char*)lsb + (wc * 64 + l15) * 64 + (lg ^ rs) * 16;

  auto stage = [&](int k0, int buf) {
#pragma unroll
    for (int i = 0; i < BM / 64; i++)
      gload16(Asrc + (size_t)i * 64 * K + k0, (char*)lsa + buf * ABUF + i * 4096 + w * 1024);
#pragma unroll
    for (int i = 0; i < 2; i++)
      gload16(Bsrc + (size_t)i * 64 * K + k0, (char*)lsb + buf * 8192 + i * 4096 + w * 1024);
  };

  stage(0, 0);
  const int NT = K >> 5;
  for (int it = 0; it < NT; it++) {
    const int buf = it & 1;
    __syncthreads();
    if (it + 1 < NT) stage((it + 1) << 5, buf ^ 1);

    const char* ap = aadr + buf * ABUF;
    const char* bp = badr + buf * 8192;
    bf16x8 af[WM], bfr[4];
#pragma unroll
    for (int m = 0; m < WM; m++)
      af[m] = *(const bf16x8*)(ap + m * 1024);
#pragma unroll
    for (int n = 0; n < 4; n++)
      bfr[n] = *(const bf16x8*)(bp + n * 1024);
#pragma unroll
    for (int m = 0; m < WM; m++)
#pragma unroll
      for (int n = 0; n < 4; n++)
        acc[m][n] = mfma16(af[m], bfr[n], acc[m][n]);
  }

#pragma unroll
  for (int m = 0; m < WM; m++) {
    const int row = m0 + wr * (BM / 2) + m * 16 + lg * 4;
#pragma unroll
    for (int n = 0; n < 4; n++) {
      const int col = n0 + wc * 64 + n * 16 + l15;
      const float bias = G.bias[col];
#pragma unroll
      for (int r = 0; r < 4; r++) {
        const float v = acc[m][n][r] + bias;
        const size_t idx = (size_t)(row + r) * N + col;
        if (EPI == 0)      G.outB[idx] = f2bf(v * G.oscale);
        else if (EPI == 1) outF[idx] = v + resid[idx];
        else               G.outB[idx] = f2bf(gelu_t(v));
      }
    }
  }
}

// ---------------- GEMM v8c (rounds 14/15 proven): BK=64, BM in {64,128} ----------------
// Row = 64 u16 = 128B = 8 chunks. Store logical chunk c of row r at physical c^(r&7).
// Read (k-half h, quarter lg, row l15): physical chunk = (h^rb)*4 + (lg^r3), rb=(l15>>2)&1, r3=l15&3.
// EPI 1: outF = acc + bias + resid (fp32); EPI 2: outB = bf16(gelu(acc+bias))
template <int EPI, int BM>
__global__ __launch_bounds__(256) void gemm5(const u16* __restrict__ A,
                                             const u16* __restrict__ W,
                                             const float* __restrict__ bias,
                                             const float* __restrict__ resid,
                                             float* __restrict__ outF,
                                             u16* __restrict__ outB,
                                             int N, int K) {
  constexpr int WM   = BM / 32;
  constexpr int ABUF = BM * 128;   // bytes per A buffer (BM rows x 128B)
  __shared__ u16 lsa[2][BM * 64];
  __shared__ u16 lsb[2][128 * 64];
  const int t = threadIdx.x;
  const int w = t >> 6, l = t & 63, l15 = l & 15, lg = l >> 4;
  const int wr = w >> 1, wc = w & 1;
  // bijective XCD-chunk remap
  const int nwg = gridDim.x * gridDim.y;
  int flat = blockIdx.y * gridDim.x + blockIdx.x;
  flat = (flat & 7) * (nwg >> 3) + (flat >> 3);
  const int bx = flat % gridDim.x, by = flat / gridDim.x;
  const int n0 = bx * 128, m0 = by * BM;

  f32x4 acc[WM][4];
#pragma unroll
  for (int m = 0; m < WM; m++)
#pragma unroll
    for (int n = 0; n < 4; n++) acc[m][n] = (f32x4){0.f, 0.f, 0.f, 0.f};

  // staging: per stage-call i, thread covers row i*32 + w*8 + (l>>3), physical chunk l&7,
  // source (logical) chunk = (l&7) ^ (row&7), with row&7 = l>>3 (i*32, w*8 are 0 mod 8).
  const int srow = w * 8 + (l >> 3);
  const int scol = 8 * ((l & 7) ^ ((l >> 3) & 7));
  const u16* Asrc = A + (size_t)(m0 + srow) * K + scol;
  const u16* Bsrc = W + (size_t)(n0 + srow) * K + scol;

  // read-side addresses (two pointers per operand: k-half 0 / k-half 1)
  const int r3 = l15 & 3, rb = (l15 >> 2) & 1;
  const int cA = lg ^ r3;
  const char* abase = (const char*)lsa + (wr * (BM / 2) + l15) * 128;
  const char* bbase = (const char*)lsb + (wc * 64 + l15) * 128;
  const char* aadr0 = abase + ((rb)     * 4 + cA) * 16;
  const char* aadr1 = abase + ((rb ^ 1) * 4 + cA) * 16;
  const char* badr0 = bbase + ((rb)     * 4 + cA) * 16;
  const char* badr1 = bbase + ((rb ^ 1) * 4 + cA) * 16;

  auto stage = [&](int k0, int buf) {
#pragma unroll
    for (int i = 0; i < BM / 32; i++)
      gload16(Asrc + (size_t)i * 32 * K + k0, (char*)lsa + buf * ABUF + i * 4096 + w * 1024);
#pragma unroll
    for (int i = 0; i < 4; i++)
      gload16(Bsrc + (size_t)i * 32 * K + k0, (char*)lsb + buf * 16384 + i * 4096 + w * 1024);
  };

  stage(0, 0);
  const int NT = K >> 6;
  for (int it = 0; it < NT; it++) {
    const int buf = it & 1;
    __syncthreads();
    if (it + 1 < NT) stage((it + 1) << 6, buf ^ 1);

    const int ao = buf * ABUF;
    const int bo = buf * 16384;
    bf16x8 af[WM][2], bfr[4][2];
#pragma unroll
    for (int m = 0; m < WM; m++) {
      af[m][0] = *(const bf16x8*)(aadr0 + ao + m * 2048);
      af[m][1] = *(const bf16x8*)(aadr1 + ao + m * 2048);
    }
#pragma unroll
    for (int n = 0; n < 4; n++) {
      bfr[n][0] = *(const bf16x8*)(badr0 + bo + n * 2048);
      bfr[n][1] = *(const bf16x8*)(badr1 + bo + n * 2048);
    }
#pragma unroll
    for (int m = 0; m < WM; m++)
#pragma unroll
      for (int n = 0; n < 4; n++) {
        acc[m][n] = mfma16(af[m][0], bfr[n][0], acc[m][n]);
        acc[m][n] = mfma16(af[m][1], bfr[n][1], acc[m][n]);
      }
  }

#pragma unroll
  for (int m = 0; m < WM; m++) {
    const int row = m0 + wr * (BM / 2) + m * 16 + lg * 4;
#pragma unroll
    for (int n = 0; n < 4; n++) {
      const int col = n0 + wc * 64 + n * 16 + l15;
      const float bc = bias[col];
#pragma unroll
      for (int r = 0; r < 4; r++) {
        const size_t idx = (size_t)(row + r) * N + col;
        const float v = acc[m][n][r] + bc;
        if (EPI == 1) outF[idx] = v + resid[idx];
        else          outB[idx] = f2bf(gelu_t(v));
      }
    }
  }
}

// ---------------- Flash attention v7 (rounds 16-18 proven): 4 waves x 32 q-rows ----------------
__global__ __launch_bounds__(256, 3) void attn7(const u16* __restrict__ q,
                                                const u16* __restrict__ k,
                                                const u16* __restrict__ vt,
                                                u16* __restrict__ o) {
  // layout: K[2][8192] @0 | V[2][8192] @16384 | P[4 waves][2 m][2048] @32768  (48KB)
  __shared__ __align__(16) char smem[49152];
  const int t = threadIdx.x, w = t >> 6, l = t & 63, l15 = l & 15, lg = l >> 4;
  int flat = blockIdx.y * gridDim.x + blockIdx.x;   // 512 blocks
  flat = (flat & 7) * 64 + (flat >> 3);             // XCD-chunked
  const int qbk = flat & 15, bh = flat >> 4;
  const int b = bh >> 4, h = bh & 15;
  const int qrow0 = b * LSEQ + qbk * 128 + w * 32;  // wave covers 32 q-rows
  const int r7 = l15 & 7;
  const int c0 = lg ^ r7;

  bf16x8 av[2][2];
#pragma unroll
  for (int m = 0; m < 2; m++)
#pragma unroll
    for (int i = 0; i < 2; i++)
      av[m][i] = *(const bf16x8*)(q + (size_t)(qrow0 + m * 16 + l15) * DIM + h * HD + i * 32 + lg * 8);

  const char* adrA  = smem + l15 * 128 + c0 * 16;
  const char* adrB  = smem + l15 * 128 + (c0 ^ 4) * 16;
  const char* padrA = smem + 32768 + w * 4096 + l15 * 128 + c0 * 16;
  const char* padrB = smem + 32768 + w * 4096 + l15 * 128 + (c0 ^ 4) * 16;
  char* pwa[4];
#pragma unroll
  for (int cb = 0; cb < 4; cb++)
    pwa[cb] = smem + 32768 + w * 4096 + l15 * 128 +
              (((2 * cb + (lg >> 1)) ^ r7) * 16) + (lg & 1) * 8;

  // staging: wave w loads rows w*16 + j*8 + (l>>3), j in {0,1}
  const int srow = l >> 3;
  const int schk = 8 * ((l & 7) ^ (srow & 7));
  const u16* ksrc = k + (size_t)(b * LSEQ + w * 16 + srow) * DIM + h * HD + schk;
  const u16* vsrc = vt + ((size_t)bh * HD + w * 16 + srow) * LSEQ + schk;

  f32x4 oacc[2][4];
#pragma unroll
  for (int m = 0; m < 2; m++)
#pragma unroll
    for (int cb = 0; cb < 4; cb++) oacc[m][cb] = (f32x4){0.f, 0.f, 0.f, 0.f};
  f32x4 minit[2] = {(f32x4){0.f, 0.f, 0.f, 0.f}, (f32x4){0.f, 0.f, 0.f, 0.f}};
  float lsum[2] = {0.f, 0.f};

  auto issueTile = [&](int jt, int buf) {
    const u16* kp = ksrc + (size_t)jt * DIM;
    const u16* vp = vsrc + jt;
#pragma unroll
    for (int j = 0; j < 2; j++) {
      gload16(kp + (size_t)j * 8 * DIM,  smem + buf * 8192 + w * 2048 + j * 1024);
      gload16(vp + (size_t)j * 8 * LSEQ, smem + 16384 + buf * 8192 + w * 2048 + j * 1024);
    }
  };

  issueTile(0, 0);
  for (int it = 0; it < LSEQ / 64; it++) {
    const int buf = it & 1;
    __syncthreads();
    if (it + 1 < LSEQ / 64) issueTile((it + 1) * 64, buf ^ 1);
    const int ko = buf * 8192;

    f32x4 s[2][4];
    const char* kA = adrA + ko;
    const char* kB = adrB + ko;
    __builtin_amdgcn_s_setprio(1);
#pragma unroll
    for (int cb = 0; cb < 4; cb++) {
      bf16x8 kf0 = *(const bf16x8*)(kA + cb * 2048);
      bf16x8 kf1 = *(const bf16x8*)(kB + cb * 2048);
      s[0][cb] = mfma16(kf0, av[0][0], minit[0]);
      s[1][cb] = mfma16(kf0, av[1][0], minit[1]);
      s[0][cb] = mfma16(kf1, av[0][1], s[0][cb]);
      s[1][cb] = mfma16(kf1, av[1][1], s[1][cb]);
    }
    __builtin_amdgcn_s_setprio(0);

    float tm[2];
#pragma unroll
    for (int m = 0; m < 2; m++)
      tm[m] = fmaxf(fmaxf(fmaxf(s[m][0][0], s[m][0][1]), fmaxf(s[m][0][2], s[m][0][3])),
                    fmaxf(fmaxf(fmaxf(s[m][1][0], s[m][1][1]), fmaxf(s[m][1][2], s[m][1][3])),
                          fmaxf(fmaxf(fmaxf(s[m][2][0], s[m][2][1]), fmaxf(s[m][2][2], s[m][2][3])),
                                fmaxf(fmaxf(s[m][3][0], s[m][3][1]), fmaxf(s[m][3][2], s[m][3][3])))));
    if (__any(fmaxf(tm[0], tm[1]) > 8.0f)) {
#pragma unroll
      for (int m = 0; m < 2; m++) {
        float tr = fmaxf(tm[m], __shfl_xor(tm[m], 16));
        tr = fmaxf(tr, __shfl_xor(tr, 32));
        const float d = fmaxf(tr, 0.f);
        const float scl = EXP2(-d);
        const f32x4 dv = (f32x4){d, d, d, d};
        lsum[m] *= scl;
        minit[m] -= dv;
#pragma unroll
        for (int cb = 0; cb < 4; cb++) s[m][cb] -= dv;
#pragma unroll
        for (int r = 0; r < 4; r++) {
          const float so = __shfl(scl, lg * 4 + r);
#pragma unroll
          for (int cb = 0; cb < 4; cb++) oacc[m][cb][r] *= so;
        }
      }
    }
#pragma unroll
    for (int m = 0; m < 2; m++) {
      float ps = 0.f;
      uint2 pk[4];
#pragma unroll
      for (int cb = 0; cb < 4; cb++) {
        float a0 = EXP2(s[m][cb][0]);
        float a1 = EXP2(s[m][cb][1]);
        float a2 = EXP2(s[m][cb][2]);
        float a3 = EXP2(s[m][cb][3]);
        ps += (a0 + a1) + (a2 + a3);
        pk[cb].x = cvtpk(a0, a1);
        pk[cb].y = cvtpk(a2, a3);
      }
      lsum[m] += ps;
#pragma unroll
      for (int cb = 0; cb < 4; cb++) *(uint2*)(pwa[cb] + m * 2048) = pk[cb];
    }

    const char* vA = adrA + ko + 16384;
    const char* vB = adrB + ko + 16384;
    bf16x8 pa0[2], pa1[2];
#pragma unroll
    for (int m = 0; m < 2; m++) {
      pa0[m] = *(const bf16x8*)(padrA + m * 2048);
      pa1[m] = *(const bf16x8*)(padrB + m * 2048);
    }
    __builtin_amdgcn_s_setprio(1);
#pragma unroll
    for (int cb = 0; cb < 4; cb++) {
      bf16x8 vf0 = *(const bf16x8*)(vA + cb * 2048);
      oacc[0][cb] = mfma16(pa0[0], vf0, oacc[0][cb]);
      oacc[1][cb] = mfma16(pa0[1], vf0, oacc[1][cb]);
    }
#pragma unroll
    for (int cb = 0; cb < 4; cb++) {
      bf16x8 vf1 = *(const bf16x8*)(vB + cb * 2048);
      oacc[0][cb] = mfma16(pa1[0], vf1, oacc[0][cb]);
      oacc[1][cb] = mfma16(pa1[1], vf1, oacc[1][cb]);
    }
    __builtin_amdgcn_s_setprio(0);
  }

#pragma unroll
  for (int m = 0; m < 2; m++) {
    float rl = lsum[m] + __shfl_xor(lsum[m], 16);
    rl += __shfl_xor(rl, 32);
#pragma unroll
    for (int r = 0; r < 4; r++) {
      const float lo = __shfl(rl, lg * 4 + r);
      const float rcp = 1.0f / lo;
#pragma unroll
      for (int cb = 0; cb < 4; cb++) {
        o[(size_t)(qrow0 + m * 16 + lg * 4 + r) * DIM + h * HD + cb * 16 + l15] =
            f2bf(oacc[m][cb][r] * rcp);
      }
    }
  }
}

extern "C" void kernel_launch(void* const* d_in, const int* in_sizes, int n_in,
                              void* d_out, int out_size, void* d_ws, size_t ws_size,
                              hipStream_t stream) {
  const float* x   = (const float*)d_in[0];
  const float* g1  = (const float*)d_in[1];
  const float* b1  = (const float*)d_in[2];
  const float* Wq  = (const float*)d_in[3];
  const float* bq  = (const float*)d_in[4];
  const float* Wk  = (const float*)d_in[5];
  const float* bk  = (const float*)d_in[6];
  const float* Wv  = (const float*)d_in[7];
  const float* bv  = (const float*)d_in[8];
  const float* Wo  = (const float*)d_in[9];
  const float* bo  = (const float*)d_in[10];
  const float* g2  = (const float*)d_in[11];
  const float* b2  = (const float*)d_in[12];
  const float* W1  = (const float*)d_in[13];
  const float* bf1 = (const float*)d_in[14];
  const float* W2  = (const float*)d_in[15];
  const float* bf2 = (const float*)d_in[16];
  float* out = (float*)d_out;

  const size_t E = (size_t)BTOK * DIM;  // 4M elems
  u16* h     = (u16*)d_ws;   // 8MB
  u16* qb    = h + E;
  u16* kbuf  = qb + E;
  u16* vbuf  = kbuf + E;
  u16* vtb   = vbuf + E;
  u16* wqkvo = vtb + E;      // 8MB bf16 Wq|Wk|Wv|Wo  (peak ws use: 48MB)
  u16* ob    = vbuf;         // attn out aliases v (dead after transpose)
  // after O-proj, q/k regions are dead:
  u16* W1b   = qb;           // 8MB
  u16* W2b   = kbuf;         // 8MB
  u16* mid   = vbuf;         // 8MB
  u16* h2    = h;
  float* x2  = out;          // attention residual lives in d_out (fp32)

  u16* Wqb = wqkvo;
  u16* Wkb = wqkvo + ((size_t)1 << 20);
  u16* Wvb = wqkvo + ((size_t)2 << 20);
  u16* Wob = wqkvo + ((size_t)3 << 20);

  // 0. QKV/O weights -> bf16
  wcvt4<<<dim3(2048), dim3(256), 0, stream>>>(Wq, Wk, Wv, Wo, wqkvo);
  // 1. LN1: x -> h (bf16)
  ln_kernel<<<dim3(BTOK), dim3(256), 0, stream>>>(x, g1, b1, h);
  // 2. fused QKV projections (q pre-scaled by SCALE*log2e); BK=32 (measured best for K=1024 x3)
  gemm3<0, 128><<<dim3(24, BTOK / 128), 256, 0, stream>>>(
      h, GArg{Wqb, bq, qb, QSCL}, GArg{Wkb, bk, kbuf, 1.0f}, GArg{Wvb, bv, vbuf, 1.0f},
      nullptr, nullptr, DIM, DIM, 8);
  // 3. V transpose
  transpose_v<<<dim3(32, 32), 256, 0, stream>>>(vbuf, vtb);
  // 4. flash attention (4 waves x 32 q-rows)
  attn7<<<dim3(LSEQ / 128, 32), 256, 0, stream>>>(qb, kbuf, vtb, ob);
  // 5. O projection + residual -> x2 (= d_out, fp32); BM=64, BK=64
  gemm5<1, 64><<<dim3(8, BTOK / 64), 256, 0, stream>>>(ob, Wob, bo, x, x2, nullptr, DIM, DIM);
  // 5b. FFN weights -> bf16 (into dead q/k regions)
  wcvt2<<<dim3(4096), dim3(256), 0, stream>>>(W1, W2, W1b, W2b);
  // 6. LN2: x2 -> h2 (bf16)
  ln_kernel<<<dim3(BTOK), dim3(256), 0, stream>>>(x2, g2, b2, h2);
  // 7. FFN1 + GELU -> mid (bf16); BM=128, BK=64
  gemm5<2, 128><<<dim3(32, BTOK / 128), 256, 0, stream>>>(h2, W1b, bf1, nullptr, nullptr, mid, FFN, DIM);
  // 8. FFN2 + residual (in-place on d_out); BM=64, BK=64
  gemm5<1, 64><<<dim3(8, BTOK / 64), 256, 0, stream>>>(mid, W2b, bf2, x2, out, nullptr, DIM, FFN);
}

// Round 20
// 230.500 us; speedup vs baseline: 1.0020x; 1.0020x over previous
//
#include <hip/hip_runtime.h>
#include <hip/hip_bf16.h>
#include <math.h>

typedef unsigned short u16;
typedef __attribute__((ext_vector_type(8))) __bf16 bf16x8;
typedef __attribute__((ext_vector_type(4))) float f32x4;

#define DIM   1024
#define LSEQ  2048
#define BTOK  4096
#define HD    64
#define FFN   4096
// 1/sqrt(64) * log2(e), folded into Q at projection time so softmax is pure exp2
#define QSCL  0.18033688011112042f

#if __has_builtin(__builtin_amdgcn_exp2f)
#define EXP2(x) __builtin_amdgcn_exp2f(x)
#else
#define EXP2(x) exp2f(x)
#endif

__device__ __forceinline__ u16 f2bf(float f) {
  unsigned u = __builtin_bit_cast(unsigned, f);
  u += 0x7FFFu + ((u >> 16) & 1u);
  return (u16)(u >> 16);
}
__device__ __forceinline__ unsigned pk2(float a, float b) {
  return (unsigned)f2bf(a) | ((unsigned)f2bf(b) << 16);
}
__device__ __forceinline__ unsigned cvtpk(float lo, float hi) {
  unsigned r;
  asm("v_cvt_pk_bf16_f32 %0, %1, %2" : "=v"(r) : "v"(lo), "v"(hi));
  return r;
}
__device__ __forceinline__ f32x4 mfma16(bf16x8 a, bf16x8 b, f32x4 c) {
  return __builtin_amdgcn_mfma_f32_16x16x32_bf16(a, b, c, 0, 0, 0);
}
__device__ __forceinline__ void gload16(const void* g, void* l) {
  __builtin_amdgcn_global_load_lds((const __attribute__((address_space(1))) char*)g,
                                   (__attribute__((address_space(3))) char*)l, 16, 0, 0);
}
// gelu (tanh form)
__device__ __forceinline__ float gelu_t(float v) {
  float v3 = v * v * v;
  float tt = fmaf(-0.10296766f, v3, -2.30258509f * v);
  return v * __builtin_amdgcn_rcpf(1.0f + EXP2(tt));
}

// ---------------- LayerNorm (fp32 in -> bf16 out) ----------------
__global__ __launch_bounds__(256) void ln_kernel(const float* __restrict__ x,
                                                 const float* __restrict__ g,
                                                 const float* __restrict__ bta,
                                                 u16* __restrict__ out) {
  int row = blockIdx.x, t = threadIdx.x;
  const float* xr = x + (size_t)row * DIM;
  float4 xv = *(const float4*)(xr + t * 4);
  float s  = xv.x + xv.y + xv.z + xv.w;
  float ss = xv.x * xv.x + xv.y * xv.y + xv.z * xv.z + xv.w * xv.w;
#pragma unroll
  for (int m = 32; m >= 1; m >>= 1) {
    s  += __shfl_xor(s, m);
    ss += __shfl_xor(ss, m);
  }
  __shared__ float red[8];
  if ((t & 63) == 0) { red[(t >> 6) * 2] = s; red[(t >> 6) * 2 + 1] = ss; }
  __syncthreads();
  s  = red[0] + red[2] + red[4] + red[6];
  ss = red[1] + red[3] + red[5] + red[7];
  float mu  = s * (1.0f / DIM);
  float var = ss * (1.0f / DIM) - mu * mu;
  float rs  = rsqrtf(var + 1e-5f);
  float4 gv = *(const float4*)(g + t * 4);
  float4 bv = *(const float4*)(bta + t * 4);
  uint2 o;
  o.x = pk2((xv.x - mu) * rs * gv.x + bv.x, (xv.y - mu) * rs * gv.y + bv.y);
  o.y = pk2((xv.z - mu) * rs * gv.z + bv.z, (xv.w - mu) * rs * gv.w + bv.w);
  *(uint2*)(out + (size_t)row * DIM + t * 4) = o;
}

// ---------------- weight fp32 -> bf16 ----------------
__global__ __launch_bounds__(256) void wcvt4(const float* __restrict__ Wq, const float* __restrict__ Wk,
                                             const float* __restrict__ Wv, const float* __restrict__ Wo,
                                             u16* __restrict__ dst) {
  int b = blockIdx.x;
  int r = b >> 9;
  const float* s = (r == 0) ? Wq : (r == 1) ? Wk : (r == 2) ? Wv : Wo;
  size_t i = (((size_t)(b & 511)) * 256 + threadIdx.x) * 8;
  float4 f0 = *(const float4*)(s + i), f1 = *(const float4*)(s + i + 4);
  uint4 o = { pk2(f0.x, f0.y), pk2(f0.z, f0.w), pk2(f1.x, f1.y), pk2(f1.z, f1.w) };
  *(uint4*)(dst + ((size_t)r << 20) + i) = o;
}
__global__ __launch_bounds__(256) void wcvt2(const float* __restrict__ W1, const float* __restrict__ W2,
                                             u16* __restrict__ d1, u16* __restrict__ d2) {
  int b = blockIdx.x;
  const float* s = (b < 2048) ? W1 : W2;
  u16* d = (b < 2048) ? d1 : d2;
  size_t i = (((size_t)(b & 2047)) * 256 + threadIdx.x) * 8;
  float4 f0 = *(const float4*)(s + i), f1 = *(const float4*)(s + i + 4);
  uint4 o = { pk2(f0.x, f0.y), pk2(f0.z, f0.w), pk2(f1.x, f1.y), pk2(f1.z, f1.w) };
  *(uint4*)(d + i) = o;
}

// ---------------- V transpose: v[b,l,h,c] -> vt[b,h,c,l] ----------------
__global__ __launch_bounds__(256) void transpose_v(const u16* __restrict__ v,
                                                   u16* __restrict__ vt) {
  __shared__ u16 tls[64][80];
  int jb = blockIdx.x, bh = blockIdx.y, b = bh >> 4, h = bh & 15;
  int t = threadIdx.x;
  int r = t >> 2, seg = t & 3;
  const u16* src = v + (size_t)(b * LSEQ + jb * 64 + r) * DIM + h * HD + seg * 16;
  *(uint4*)&tls[r][seg * 16]     = *(const uint4*)src;
  *(uint4*)&tls[r][seg * 16 + 8] = *(const uint4*)(src + 8);
  __syncthreads();
  int c = t >> 2, jseg = t & 3;
  u16 tmp[16] __attribute__((aligned(16)));
#pragma unroll
  for (int i = 0; i < 16; i++) tmp[i] = tls[jseg * 16 + i][c];
  u16* dst = vt + ((size_t)bh * HD + c) * LSEQ + jb * 64 + jseg * 16;
  *(uint4*)dst       = *(const uint4*)tmp;
  *(uint4*)(dst + 8) = *(const uint4*)(tmp + 8);
}

// ---------------- GEMM (round-5 proven, BK=32): C = A(bf16) @ W(bf16,[N,K])^T + bias ----------------
// EPI 0: outB = bf16((acc+bias)*oscale); 1: outF = acc+bias+resid (fp32); 2: outB = bf16(gelu(acc+bias))
struct GArg { const u16* Wb; const float* bias; u16* outB; float oscale; };

template <int EPI, int BM>
__global__ __launch_bounds__(256) void gemm3(const u16* __restrict__ A,
                                             GArg g0, GArg g1, GArg g2,
                                             const float* __restrict__ resid,
                                             float* __restrict__ outF,
                                             int N, int K, int nbPerW) {
  constexpr int WM = BM / 32;
  constexpr int ABUF = BM * 64;  // bytes per A double-buffer half
  __shared__ u16 lsa[2][BM * 32];
  __shared__ u16 lsb[2][128 * 32];
  const int t = threadIdx.x;
  const int w = t >> 6, l = t & 63, l15 = l & 15, lg = l >> 4;
  const int wr = w >> 1, wc = w & 1;
  // bijective XCD-chunk remap (all launch grids have nwg % 8 == 0)
  const int nwg = gridDim.x * gridDim.y;
  int flat = blockIdx.y * gridDim.x + blockIdx.x;
  flat = (flat & 7) * (nwg >> 3) + (flat >> 3);
  const int bx = flat % gridDim.x, by = flat / gridDim.x;
  const int sel = bx / nbPerW, nb = bx % nbPerW;
  GArg G = (sel == 0) ? g0 : ((sel == 1) ? g1 : g2);
  const int n0 = nb * 128, m0 = by * BM;

  f32x4 acc[WM][4];
#pragma unroll
  for (int m = 0; m < WM; m++)
#pragma unroll
    for (int n = 0; n < 4; n++) acc[m][n] = (f32x4){0.f, 0.f, 0.f, 0.f};

  // staging: linear LDS dest, pre-swizzled global source (chunk ^= (row>>1)&3)
  const int grow = t >> 2;
  const int gcol = 8 * ((t & 3) ^ ((t >> 3) & 3));
  const u16* Asrc = A + (size_t)(m0 + grow) * K + gcol;
  const u16* Bsrc = G.Wb + (size_t)(n0 + grow) * K + gcol;
  const int rs = (l15 >> 1) & 3;  // read-side swizzle key

  const char* aadr = (const char*)lsa + (wr * (BM / 2) + l15) * 64 + (lg ^ rs) * 16;
  const char* badr = (const char*)lsb + (wc * 64 + l15) * 64 + (lg ^ rs) * 16;

  auto stage = [&](int k0, int buf) {
#pragma unroll
    for (int i = 0; i < BM / 64; i++)
      gload16(Asrc + (size_t)i * 64 * K + k0, (char*)lsa + buf * ABUF + i * 4096 + w * 1024);
#pragma unroll
    for (int i = 0; i < 2; i++)
      gload16(Bsrc + (size_t)i * 64 * K + k0, (char*)lsb + buf * 8192 + i * 4096 + w * 1024);
  };

  stage(0, 0);
  const int NT = K >> 5;
  for (int it = 0; it < NT; it++) {
    const int buf = it & 1;
    __syncthreads();
    if (it + 1 < NT) stage((it + 1) << 5, buf ^ 1);

    const char* ap = aadr + buf * ABUF;
    const char* bp = badr + buf * 8192;
    bf16x8 af[WM], bfr[4];
#pragma unroll
    for (int m = 0; m < WM; m++)
      af[m] = *(const bf16x8*)(ap + m * 1024);
#pragma unroll
    for (int n = 0; n < 4; n++)
      bfr[n] = *(const bf16x8*)(bp + n * 1024);
#pragma unroll
    for (int m = 0; m < WM; m++)
#pragma unroll
      for (int n = 0; n < 4; n++)
        acc[m][n] = mfma16(af[m], bfr[n], acc[m][n]);
  }

#pragma unroll
  for (int m = 0; m < WM; m++) {
    const int row = m0 + wr * (BM / 2) + m * 16 + lg * 4;
#pragma unroll
    for (int n = 0; n < 4; n++) {
      const int col = n0 + wc * 64 + n * 16 + l15;
      const float bias = G.bias[col];
#pragma unroll
      for (int r = 0; r < 4; r++) {
        const float v = acc[m][n][r] + bias;
        const size_t idx = (size_t)(row + r) * N + col;
        if (EPI == 0)      G.outB[idx] = f2bf(v * G.oscale);
        else if (EPI == 1) outF[idx] = v + resid[idx];
        else               G.outB[idx] = f2bf(gelu_t(v));
      }
    }
  }
}

// ---------------- GEMM v8c (rounds 14/15 proven): BK=64, BM in {64,128} ----------------
// Row = 64 u16 = 128B = 8 chunks. Store logical chunk c of row r at physical c^(r&7).
// Read (k-half h, quarter lg, row l15): physical chunk = (h^rb)*4 + (lg^r3), rb=(l15>>2)&1, r3=l15&3.
// EPI 1: outF = acc + bias + resid (fp32); EPI 2: outB = bf16(gelu(acc+bias))
template <int EPI, int BM>
__global__ __launch_bounds__(256) void gemm5(const u16* __restrict__ A,
                                             const u16* __restrict__ W,
                                             const float* __restrict__ bias,
                                             const float* __restrict__ resid,
                                             float* __restrict__ outF,
                                             u16* __restrict__ outB,
                                             int N, int K) {
  constexpr int WM   = BM / 32;
  constexpr int ABUF = BM * 128;   // bytes per A buffer (BM rows x 128B)
  __shared__ u16 lsa[2][BM * 64];
  __shared__ u16 lsb[2][128 * 64];
  const int t = threadIdx.x;
  const int w = t >> 6, l = t & 63, l15 = l & 15, lg = l >> 4;
  const int wr = w >> 1, wc = w & 1;
  // bijective XCD-chunk remap
  const int nwg = gridDim.x * gridDim.y;
  int flat = blockIdx.y * gridDim.x + blockIdx.x;
  flat = (flat & 7) * (nwg >> 3) + (flat >> 3);
  const int bx = flat % gridDim.x, by = flat / gridDim.x;
  const int n0 = bx * 128, m0 = by * BM;

  f32x4 acc[WM][4];
#pragma unroll
  for (int m = 0; m < WM; m++)
#pragma unroll
    for (int n = 0; n < 4; n++) acc[m][n] = (f32x4){0.f, 0.f, 0.f, 0.f};

  // staging: per stage-call i, thread covers row i*32 + w*8 + (l>>3), physical chunk l&7,
  // source (logical) chunk = (l&7) ^ (row&7), with row&7 = l>>3 (i*32, w*8 are 0 mod 8).
  const int srow = w * 8 + (l >> 3);
  const int scol = 8 * ((l & 7) ^ ((l >> 3) & 7));
  const u16* Asrc = A + (size_t)(m0 + srow) * K + scol;
  const u16* Bsrc = W + (size_t)(n0 + srow) * K + scol;

  // read-side addresses (two pointers per operand: k-half 0 / k-half 1)
  const int r3 = l15 & 3, rb = (l15 >> 2) & 1;
  const int cA = lg ^ r3;
  const char* abase = (const char*)lsa + (wr * (BM / 2) + l15) * 128;
  const char* bbase = (const char*)lsb + (wc * 64 + l15) * 128;
  const char* aadr0 = abase + ((rb)     * 4 + cA) * 16;
  const char* aadr1 = abase + ((rb ^ 1) * 4 + cA) * 16;
  const char* badr0 = bbase + ((rb)     * 4 + cA) * 16;
  const char* badr1 = bbase + ((rb ^ 1) * 4 + cA) * 16;

  auto stage = [&](int k0, int buf) {
#pragma unroll
    for (int i = 0; i < BM / 32; i++)
      gload16(Asrc + (size_t)i * 32 * K + k0, (char*)lsa + buf * ABUF + i * 4096 + w * 1024);
#pragma unroll
    for (int i = 0; i < 4; i++)
      gload16(Bsrc + (size_t)i * 32 * K + k0, (char*)lsb + buf * 16384 + i * 4096 + w * 1024);
  };

  stage(0, 0);
  const int NT = K >> 6;
  for (int it = 0; it < NT; it++) {
    const int buf = it & 1;
    __syncthreads();
    if (it + 1 < NT) stage((it + 1) << 6, buf ^ 1);

    const int ao = buf * ABUF;
    const int bo = buf * 16384;
    bf16x8 af[WM][2], bfr[4][2];
#pragma unroll
    for (int m = 0; m < WM; m++) {
      af[m][0] = *(const bf16x8*)(aadr0 + ao + m * 2048);
      af[m][1] = *(const bf16x8*)(aadr1 + ao + m * 2048);
    }
#pragma unroll
    for (int n = 0; n < 4; n++) {
      bfr[n][0] = *(const bf16x8*)(badr0 + bo + n * 2048);
      bfr[n][1] = *(const bf16x8*)(badr1 + bo + n * 2048);
    }
#pragma unroll
    for (int m = 0; m < WM; m++)
#pragma unroll
      for (int n = 0; n < 4; n++) {
        acc[m][n] = mfma16(af[m][0], bfr[n][0], acc[m][n]);
        acc[m][n] = mfma16(af[m][1], bfr[n][1], acc[m][n]);
      }
  }

#pragma unroll
  for (int m = 0; m < WM; m++) {
    const int row = m0 + wr * (BM / 2) + m * 16 + lg * 4;
#pragma unroll
    for (int n = 0; n < 4; n++) {
      const int col = n0 + wc * 64 + n * 16 + l15;
      const float bc = bias[col];
#pragma unroll
      for (int r = 0; r < 4; r++) {
        const size_t idx = (size_t)(row + r) * N + col;
        const float v = acc[m][n][r] + bc;
        if (EPI == 1) outF[idx] = v + resid[idx];
        else          outB[idx] = f2bf(gelu_t(v));
      }
    }
  }
}

// ---------------- Flash attention v7 (rounds 16-19 proven): 4 waves x 32 q-rows ----------------
__global__ __launch_bounds__(256, 3) void attn7(const u16* __restrict__ q,
                                                const u16* __restrict__ k,
                                                const u16* __restrict__ vt,
                                                u16* __restrict__ o) {
  // layout: K[2][8192] @0 | V[2][8192] @16384 | P[4 waves][2 m][2048] @32768  (48KB)
  __shared__ __align__(16) char smem[49152];
  const int t = threadIdx.x, w = t >> 6, l = t & 63, l15 = l & 15, lg = l >> 4;
  int flat = blockIdx.y * gridDim.x + blockIdx.x;   // 512 blocks
  flat = (flat & 7) * 64 + (flat >> 3);             // XCD-chunked
  const int qbk = flat & 15, bh = flat >> 4;
  const int b = bh >> 4, h = bh & 15;
  const int qrow0 = b * LSEQ + qbk * 128 + w * 32;  // wave covers 32 q-rows
  const int r7 = l15 & 7;
  const int c0 = lg ^ r7;

  bf16x8 av[2][2];
#pragma unroll
  for (int m = 0; m < 2; m++)
#pragma unroll
    for (int i = 0; i < 2; i++)
      av[m][i] = *(const bf16x8*)(q + (size_t)(qrow0 + m * 16 + l15) * DIM + h * HD + i * 32 + lg * 8);

  const char* adrA  = smem + l15 * 128 + c0 * 16;
  const char* adrB  = smem + l15 * 128 + (c0 ^ 4) * 16;
  const char* padrA = smem + 32768 + w * 4096 + l15 * 128 + c0 * 16;
  const char* padrB = smem + 32768 + w * 4096 + l15 * 128 + (c0 ^ 4) * 16;
  char* pwa[4];
#pragma unroll
  for (int cb = 0; cb < 4; cb++)
    pwa[cb] = smem + 32768 + w * 4096 + l15 * 128 +
              (((2 * cb + (lg >> 1)) ^ r7) * 16) + (lg & 1) * 8;

  // staging: wave w loads rows w*16 + j*8 + (l>>3), j in {0,1}
  const int srow = l >> 3;
  const int schk = 8 * ((l & 7) ^ (srow & 7));
  const u16* ksrc = k + (size_t)(b * LSEQ + w * 16 + srow) * DIM + h * HD + schk;
  const u16* vsrc = vt + ((size_t)bh * HD + w * 16 + srow) * LSEQ + schk;

  f32x4 oacc[2][4];
#pragma unroll
  for (int m = 0; m < 2; m++)
#pragma unroll
    for (int cb = 0; cb < 4; cb++) oacc[m][cb] = (f32x4){0.f, 0.f, 0.f, 0.f};
  f32x4 minit[2] = {(f32x4){0.f, 0.f, 0.f, 0.f}, (f32x4){0.f, 0.f, 0.f, 0.f}};
  float lsum[2] = {0.f, 0.f};

  auto issueTile = [&](int jt, int buf) {
    const u16* kp = ksrc + (size_t)jt * DIM;
    const u16* vp = vsrc + jt;
#pragma unroll
    for (int j = 0; j < 2; j++) {
      gload16(kp + (size_t)j * 8 * DIM,  smem + buf * 8192 + w * 2048 + j * 1024);
      gload16(vp + (size_t)j * 8 * LSEQ, smem + 16384 + buf * 8192 + w * 2048 + j * 1024);
    }
  };

  issueTile(0, 0);
  for (int it = 0; it < LSEQ / 64; it++) {
    const int buf = it & 1;
    __syncthreads();
    if (it + 1 < LSEQ / 64) issueTile((it + 1) * 64, buf ^ 1);
    const int ko = buf * 8192;

    f32x4 s[2][4];
    const char* kA = adrA + ko;
    const char* kB = adrB + ko;
    __builtin_amdgcn_s_setprio(1);
#pragma unroll
    for (int cb = 0; cb < 4; cb++) {
      bf16x8 kf0 = *(const bf16x8*)(kA + cb * 2048);
      bf16x8 kf1 = *(const bf16x8*)(kB + cb * 2048);
      s[0][cb] = mfma16(kf0, av[0][0], minit[0]);
      s[1][cb] = mfma16(kf0, av[1][0], minit[1]);
      s[0][cb] = mfma16(kf1, av[0][1], s[0][cb]);
      s[1][cb] = mfma16(kf1, av[1][1], s[1][cb]);
    }
    __builtin_amdgcn_s_setprio(0);

    float tm[2];
#pragma unroll
    for (int m = 0; m < 2; m++)
      tm[m] = fmaxf(fmaxf(fmaxf(s[m][0][0], s[m][0][1]), fmaxf(s[m][0][2], s[m][0][3])),
                    fmaxf(fmaxf(fmaxf(s[m][1][0], s[m][1][1]), fmaxf(s[m][1][2], s[m][1][3])),
                          fmaxf(fmaxf(fmaxf(s[m][2][0], s[m][2][1]), fmaxf(s[m][2][2], s[m][2][3])),
                                fmaxf(fmaxf(s[m][3][0], s[m][3][1]), fmaxf(s[m][3][2], s[m][3][3])))));
    if (__any(fmaxf(tm[0], tm[1]) > 8.0f)) {
#pragma unroll
      for (int m = 0; m < 2; m++) {
        float tr = fmaxf(tm[m], __shfl_xor(tm[m], 16));
        tr = fmaxf(tr, __shfl_xor(tr, 32));
        const float d = fmaxf(tr, 0.f);
        const float scl = EXP2(-d);
        const f32x4 dv = (f32x4){d, d, d, d};
        lsum[m] *= scl;
        minit[m] -= dv;
#pragma unroll
        for (int cb = 0; cb < 4; cb++) s[m][cb] -= dv;
#pragma unroll
        for (int r = 0; r < 4; r++) {
          const float so = __shfl(scl, lg * 4 + r);
#pragma unroll
          for (int cb = 0; cb < 4; cb++) oacc[m][cb][r] *= so;
        }
      }
    }
#pragma unroll
    for (int m = 0; m < 2; m++) {
      float ps = 0.f;
      uint2 pk[4];
#pragma unroll
      for (int cb = 0; cb < 4; cb++) {
        float a0 = EXP2(s[m][cb][0]);
        float a1 = EXP2(s[m][cb][1]);
        float a2 = EXP2(s[m][cb][2]);
        float a3 = EXP2(s[m][cb][3]);
        ps += (a0 + a1) + (a2 + a3);
        pk[cb].x = cvtpk(a0, a1);
        pk[cb].y = cvtpk(a2, a3);
      }
      lsum[m] += ps;
#pragma unroll
      for (int cb = 0; cb < 4; cb++) *(uint2*)(pwa[cb] + m * 2048) = pk[cb];
    }

    const char* vA = adrA + ko + 16384;
    const char* vB = adrB + ko + 16384;
    bf16x8 pa0[2], pa1[2];
#pragma unroll
    for (int m = 0; m < 2; m++) {
      pa0[m] = *(const bf16x8*)(padrA + m * 2048);
      pa1[m] = *(const bf16x8*)(padrB + m * 2048);
    }
    __builtin_amdgcn_s_setprio(1);
#pragma unroll
    for (int cb = 0; cb < 4; cb++) {
      bf16x8 vf0 = *(const bf16x8*)(vA + cb * 2048);
      oacc[0][cb] = mfma16(pa0[0], vf0, oacc[0][cb]);
      oacc[1][cb] = mfma16(pa0[1], vf0, oacc[1][cb]);
    }
#pragma unroll
    for (int cb = 0; cb < 4; cb++) {
      bf16x8 vf1 = *(const bf16x8*)(vB + cb * 2048);
      oacc[0][cb] = mfma16(pa1[0], vf1, oacc[0][cb]);
      oacc[1][cb] = mfma16(pa1[1], vf1, oacc[1][cb]);
    }
    __builtin_amdgcn_s_setprio(0);
  }

#pragma unroll
  for (int m = 0; m < 2; m++) {
    float rl = lsum[m] + __shfl_xor(lsum[m], 16);
    rl += __shfl_xor(rl, 32);
#pragma unroll
    for (int r = 0; r < 4; r++) {
      const float lo = __shfl(rl, lg * 4 + r);
      const float rcp = 1.0f / lo;
#pragma unroll
      for (int cb = 0; cb < 4; cb++) {
        o[(size_t)(qrow0 + m * 16 + lg * 4 + r) * DIM + h * HD + cb * 16 + l15] =
            f2bf(oacc[m][cb][r] * rcp);
      }
    }
  }
}

extern "C" void kernel_launch(void* const* d_in, const int* in_sizes, int n_in,
                              void* d_out, int out_size, void* d_ws, size_t ws_size,
                              hipStream_t stream) {
  const float* x   = (const float*)d_in[0];
  const float* g1  = (const float*)d_in[1];
  const float* b1  = (const float*)d_in[2];
  const float* Wq  = (const float*)d_in[3];
  const float* bq  = (const float*)d_in[4];
  const float* Wk  = (const float*)d_in[5];
  const float* bk  = (const float*)d_in[6];
  const float* Wv  = (const float*)d_in[7];
  const float* bv  = (const float*)d_in[8];
  const float* Wo  = (const float*)d_in[9];
  const float* bo  = (const float*)d_in[10];
  const float* g2  = (const float*)d_in[11];
  const float* b2  = (const float*)d_in[12];
  const float* W1  = (const float*)d_in[13];
  const float* bf1 = (const float*)d_in[14];
  const float* W2  = (const float*)d_in[15];
  const float* bf2 = (const float*)d_in[16];
  float* out = (float*)d_out;

  const size_t E = (size_t)BTOK * DIM;  // 4M elems
  u16* h     = (u16*)d_ws;   // 8MB
  u16* qb    = h + E;
  u16* kbuf  = qb + E;
  u16* vbuf  = kbuf + E;
  u16* vtb   = vbuf + E;
  u16* wqkvo = vtb + E;      // 8MB bf16 Wq|Wk|Wv|Wo  (peak ws use: 48MB)
  u16* ob    = vbuf;         // attn out aliases v (dead after transpose)
  // after O-proj, q/k regions are dead:
  u16* W1b   = qb;           // 8MB
  u16* W2b   = kbuf;         // 8MB
  u16* mid   = vbuf;         // 8MB
  u16* h2    = h;
  float* x2  = out;          // attention residual lives in d_out (fp32)

  u16* Wqb = wqkvo;
  u16* Wkb = wqkvo + ((size_t)1 << 20);
  u16* Wvb = wqkvo + ((size_t)2 << 20);
  u16* Wob = wqkvo + ((size_t)3 << 20);

  // 0. QKV/O weights -> bf16
  wcvt4<<<dim3(2048), dim3(256), 0, stream>>>(Wq, Wk, Wv, Wo, wqkvo);
  // 1. LN1: x -> h (bf16)
  ln_kernel<<<dim3(BTOK), dim3(256), 0, stream>>>(x, g1, b1, h);
  // 2. fused QKV projections (q pre-scaled by SCALE*log2e); BK=32 (measured best for K=1024 x3)
  gemm3<0, 128><<<dim3(24, BTOK / 128), 256, 0, stream>>>(
      h, GArg{Wqb, bq, qb, QSCL}, GArg{Wkb, bk, kbuf, 1.0f}, GArg{Wvb, bv, vbuf, 1.0f},
      nullptr, nullptr, DIM, DIM, 8);
  // 3. V transpose
  transpose_v<<<dim3(32, 32), 256, 0, stream>>>(vbuf, vtb);
  // 4. flash attention (4 waves x 32 q-rows)
  attn7<<<dim3(LSEQ / 128, 32), 256, 0, stream>>>(qb, kbuf, vtb, ob);
  // 5. O projection + residual -> x2 (= d_out, fp32); BM=64, BK=64
  gemm5<1, 64><<<dim3(8, BTOK / 64), 256, 0, stream>>>(ob, Wob, bo, x, x2, nullptr, DIM, DIM);
  // 5b. FFN weights -> bf16 (into dead q/k regions)
  wcvt2<<<dim3(4096), dim3(256), 0, stream>>>(W1, W2, W1b, W2b);
  // 6. LN2: x2 -> h2 (bf16)
  ln_kernel<<<dim3(BTOK), dim3(256), 0, stream>>>(x2, g2, b2, h2);
  // 7. FFN1 + GELU -> mid (bf16); BM=128, BK=64
  gemm5<2, 128><<<dim3(32, BTOK / 128), 256, 0, stream>>>(h2, W1b, bf1, nullptr, nullptr, mid, FFN, DIM);
  // 8. FFN2 + residual (in-place on d_out); BM=64, BK=64
  gemm5<1, 64><<<dim3(8, BTOK / 64), 256, 0, stream>>>(mid, W2b, bf2, x2, out, nullptr, DIM, FFN);
}